// Round 4
// baseline (613.849 us; speedup 1.0000x reference)
//
#include <hip/hip_runtime.h>
#include <math.h>

#define HD    256
#define NHEAD 4
#define NSEG  1024

typedef short bf16x8 __attribute__((ext_vector_type(8)));
typedef float f32x16 __attribute__((ext_vector_type(16)));

__device__ __forceinline__ float tanh_fast(float v) {
    float e = __expf(2.0f * v);                    // overflow->inf, tanh->1: ok
    return 1.0f - 2.0f * __builtin_amdgcn_rcpf(e + 1.0f);
}

// split fp32 pair into packed bf16-hi word and bf16-lo word (truncation split;
// lo captures mantissa bits 9..17 -> per-product rel err ~2^-17)
__device__ __forceinline__ void split2(float a, float b, unsigned &hi, unsigned &lo) {
    unsigned ba = __float_as_uint(a), bb = __float_as_uint(b);
    unsigned ha = ba & 0xFFFF0000u, hb = bb & 0xFFFF0000u;
    float la = a - __uint_as_float(ha);
    float lb = b - __uint_as_float(hb);
    hi = (ha >> 16) | hb;
    lo = (__float_as_uint(la) >> 16) | (__float_as_uint(lb) & 0xFFFF0000u);
}

// ---------------------------------------------------------------------------
// K1: logits = tanh(x @ W1 + b1) @ W2 + b2  via split-bf16 MFMA.
// 512 thr = 8 waves: rg = wid>>2 (2 row groups x 128 rows), cgp = wid&3
// (4 col groups x 64 cols). Wave tile: 128 rows x 64 cols = 4 rt x 2 ct of
// 32x32 mfma (rt=4 keeps B LDS traffic at ~85 B/cyc/CU, under the 128 B/cyc
// ceiling; rt=2 needed 171). W1 staged in KC=128 chunks as bf16 hi/lo planes,
// [col][k] layout, 16B-slot XOR swizzle, ds_write_b128 staging (bank-clean).
// acc = 128 AGPR; launch_bounds(512,2) caps VGPR at 128 (2 waves/SIMD).
// ---------------------------------------------------------------------------
#define K1_THREADS 512
#define BM 256
#define KC 128
#define K1_LDS 131072

__global__ __launch_bounds__(K1_THREADS, 2) void k1_mfma(
    const float* __restrict__ x, const float* __restrict__ W1,
    const float* __restrict__ b1, const float* __restrict__ W2,
    const float* __restrict__ b2, float* __restrict__ out_lg, int N)
{
    extern __shared__ __align__(16) char smem[];   // [0,64K) w_hi, [64K,128K) w_lo

    const int tid  = threadIdx.x;
    const int lane = tid & 63;
    const int lo5  = lane & 31;
    const int hi   = lane >> 5;
    const int wid  = tid >> 6;
    const int rg   = wid >> 2;                     // 0..1
    const int cgp  = wid & 3;                      // 0..3
    const int C0   = cgp * 64;
    const int blkrow = blockIdx.x * BM;

    f32x16 acc[4][2];
    #pragma unroll
    for (int ct = 0; ct < 2; ++ct) {
        float b1v = b1[C0 + ct*32 + lo5];
        #pragma unroll
        for (int rt = 0; rt < 4; ++rt)
            #pragma unroll
            for (int e = 0; e < 16; ++e)
                acc[rt][ct][e] = b1v;
    }

    int rA[4];
    #pragma unroll
    for (int rt = 0; rt < 4; ++rt) {
        int r = blkrow + rg*128 + rt*32 + lo5;
        rA[rt] = r < N ? r : N - 1;                // tail clamp; writes guarded
    }

    const int colS  = tid & 255;                   // staging: thread -> (col, k-half)
    const int khalf = tid >> 8;                    // 0..1 -> k 0..63 / 64..127
    const unsigned swzS = (colS & 7) << 4;

    for (int kc = 0; kc < HD; kc += KC) {
        __syncthreads();                           // LDS reuse guard
        {   // stage W1 chunk -> bf16 hi/lo planes, [col][k], swizzled, b128 writes
            const float* wb = W1 + (size_t)(kc + khalf*64) * HD + colS;
            #pragma unroll
            for (int i = 0; i < 8; ++i) {          // 8 k-values per write
                unsigned hw[4], lw[4];
                #pragma unroll
                for (int p = 0; p < 4; ++p) {
                    float w0 = wb[(i*8 + 2*p)     * HD];
                    float w1 = wb[(i*8 + 2*p + 1) * HD];
                    split2(w0, w1, hw[p], lw[p]);
                }
                int off = colS*256 + (((khalf*64 + i*8)*2) ^ swzS);
                *(uint4*)(smem + off)         = make_uint4(hw[0], hw[1], hw[2], hw[3]);
                *(uint4*)(smem + 65536 + off) = make_uint4(lw[0], lw[1], lw[2], lw[3]);
            }
        }
        __syncthreads();

        #pragma unroll
        for (int ks = 0; ks < KC/16; ++ks) {       // 8 k-steps of 16
            union { unsigned u[4]; bf16x8 v; } ah[4], al[4];
            #pragma unroll
            for (int rt = 0; rt < 4; ++rt) {       // A: x direct from global, split in-reg
                const float* xp = x + (size_t)rA[rt]*HD + kc + ks*16 + hi*8;
                float4 q0 = *(const float4*)xp;
                float4 q1 = *(const float4*)(xp + 4);
                split2(q0.x, q0.y, ah[rt].u[0], al[rt].u[0]);
                split2(q0.z, q0.w, ah[rt].u[1], al[rt].u[1]);
                split2(q1.x, q1.y, ah[rt].u[2], al[rt].u[2]);
                split2(q1.z, q1.w, ah[rt].u[3], al[rt].u[3]);
            }
            bf16x8 bh[2], bl[2];
            #pragma unroll
            for (int ct = 0; ct < 2; ++ct) {
                int colB = C0 + ct*32 + lo5;
                int off  = colB*256 + (((ks*16 + hi*8)*2) ^ ((colB & 7) << 4));
                bh[ct] = *(const bf16x8*)(smem + off);
                bl[ct] = *(const bf16x8*)(smem + 65536 + off);
            }
            #pragma unroll
            for (int rt = 0; rt < 4; ++rt)
                #pragma unroll
                for (int ct = 0; ct < 2; ++ct) {
                    acc[rt][ct] = __builtin_amdgcn_mfma_f32_32x32x16_bf16(ah[rt].v, bh[ct], acc[rt][ct], 0, 0, 0);
                    acc[rt][ct] = __builtin_amdgcn_mfma_f32_32x32x16_bf16(ah[rt].v, bl[ct], acc[rt][ct], 0, 0, 0);
                    acc[rt][ct] = __builtin_amdgcn_mfma_f32_32x32x16_bf16(al[rt].v, bh[ct], acc[rt][ct], 0, 0, 0);
                }
        }
    }

    // epilogue: tanh -> h@W2 partial per lane -> butterfly over 32-lane half
    #pragma unroll
    for (int rt = 0; rt < 4; ++rt)
        #pragma unroll
        for (int ct = 0; ct < 2; ++ct)
            #pragma unroll
            for (int e = 0; e < 16; ++e)
                acc[rt][ct][e] = tanh_fast(acc[rt][ct][e]);

    float4 w2v[2];
    #pragma unroll
    for (int ct = 0; ct < 2; ++ct)
        w2v[ct] = *(const float4*)(W2 + (size_t)(C0 + ct*32 + lo5) * NHEAD);

    float4 mine[2];
    mine[0] = make_float4(0.f, 0.f, 0.f, 0.f);
    mine[1] = make_float4(0.f, 0.f, 0.f, 0.f);
    #pragma unroll
    for (int rt = 0; rt < 4; ++rt) {
        #pragma unroll
        for (int e = 0; e < 16; ++e) {
            float s0 = 0.f, s1 = 0.f, s2 = 0.f, s3 = 0.f;
            #pragma unroll
            for (int ct = 0; ct < 2; ++ct) {
                float t = acc[rt][ct][e];
                s0 = fmaf(t, w2v[ct].x, s0);
                s1 = fmaf(t, w2v[ct].y, s1);
                s2 = fmaf(t, w2v[ct].z, s2);
                s3 = fmaf(t, w2v[ct].w, s3);
            }
            #pragma unroll
            for (int o = 16; o >= 1; o >>= 1) {    // offsets <32: halves stay separate
                s0 += __shfl_xor(s0, o, 64);
                s1 += __shfl_xor(s1, o, 64);
                s2 += __shfl_xor(s2, o, 64);
                s3 += __shfl_xor(s3, o, 64);
            }
            if (lo5 == (rt & 1)*16 + e) mine[rt >> 1] = make_float4(s0, s1, s2, s3);
        }
    }

    __syncthreads();                               // compute done; reuse smem
    float (*p_lds)[256][4] = (float(*)[256][4])smem;   // [cgp][row][4], 16 KiB
    #pragma unroll
    for (int m = 0; m < 2; ++m) {
        int rt_m = m*2 + (lo5 >> 4);
        int e_m  = lo5 & 15;
        int row  = rg*128 + rt_m*32 + (e_m & 3) + 8*(e_m >> 2) + 4*hi;
        *(float4*)p_lds[cgp][row] = mine[m];
    }
    __syncthreads();
    if (tid < BM) {
        int grow = blkrow + tid;
        if (grow < N) {
            float4 a0 = *(float4*)p_lds[0][tid];
            float4 a1 = *(float4*)p_lds[1][tid];
            float4 a2 = *(float4*)p_lds[2][tid];
            float4 a3 = *(float4*)p_lds[3][tid];
            float4 o;
            o.x = a0.x + a1.x + a2.x + a3.x + b2[0];
            o.y = a0.y + a1.y + a2.y + a3.y + b2[1];
            o.z = a0.z + a1.z + a2.z + a3.z + b2[2];
            o.w = a0.w + a1.w + a2.w + a3.w + b2[3];
            *(float4*)(out_lg + (size_t)grow * NHEAD) = o;
        }
    }
}

// ---------------------------------------------------------------------------
__device__ __forceinline__ int lower_bound(const int* __restrict__ a, int n, int v) {
    int lo = 0, hi = n;
    while (lo < hi) { int m = (lo + hi) >> 1; if (a[m] < v) lo = m + 1; else hi = m; }
    return lo;
}

// ---------------------------------------------------------------------------
// K2: per-segment max & sum-of-exp of logits; stats stashed at out[b*256+0..7]
// ---------------------------------------------------------------------------
__global__ __launch_bounds__(256) void k2_seg(
    const int* __restrict__ batch, const float* __restrict__ lg,
    float* __restrict__ out, int N)
{
    const int b = blockIdx.x;
    const int tid = threadIdx.x;
    const int lane = tid & 63, wid = tid >> 6;
    const int start = lower_bound(batch, N, b);
    const int end   = lower_bound(batch, N, b + 1);
    const float4* lg4 = (const float4*)lg;

    float4 mx = make_float4(-INFINITY, -INFINITY, -INFINITY, -INFINITY);
    for (int i = start + tid; i < end; i += 256) {
        float4 l = lg4[i];
        mx.x = fmaxf(mx.x, l.x); mx.y = fmaxf(mx.y, l.y);
        mx.z = fmaxf(mx.z, l.z); mx.w = fmaxf(mx.w, l.w);
    }
    #pragma unroll
    for (int ofs = 32; ofs >= 1; ofs >>= 1) {
        mx.x = fmaxf(mx.x, __shfl_xor(mx.x, ofs, 64));
        mx.y = fmaxf(mx.y, __shfl_xor(mx.y, ofs, 64));
        mx.z = fmaxf(mx.z, __shfl_xor(mx.z, ofs, 64));
        mx.w = fmaxf(mx.w, __shfl_xor(mx.w, ofs, 64));
    }
    __shared__ float4 red[4];
    if (lane == 0) red[wid] = mx;
    __syncthreads();
    float4 smax;
    smax.x = fmaxf(fmaxf(red[0].x, red[1].x), fmaxf(red[2].x, red[3].x));
    smax.y = fmaxf(fmaxf(red[0].y, red[1].y), fmaxf(red[2].y, red[3].y));
    smax.z = fmaxf(fmaxf(red[0].z, red[1].z), fmaxf(red[2].z, red[3].z));
    smax.w = fmaxf(fmaxf(red[0].w, red[1].w), fmaxf(red[2].w, red[3].w));
    __syncthreads();

    float4 sm = make_float4(0.f, 0.f, 0.f, 0.f);
    for (int i = start + tid; i < end; i += 256) {
        float4 l = lg4[i];
        sm.x += __expf(l.x - smax.x); sm.y += __expf(l.y - smax.y);
        sm.z += __expf(l.z - smax.z); sm.w += __expf(l.w - smax.w);
    }
    #pragma unroll
    for (int ofs = 32; ofs >= 1; ofs >>= 1) {
        sm.x += __shfl_xor(sm.x, ofs, 64);
        sm.y += __shfl_xor(sm.y, ofs, 64);
        sm.z += __shfl_xor(sm.z, ofs, 64);
        sm.w += __shfl_xor(sm.w, ofs, 64);
    }
    if (lane == 0) red[wid] = sm;
    __syncthreads();
    if (tid == 0) {
        float4 ssum;
        ssum.x = red[0].x + red[1].x + red[2].x + red[3].x;
        ssum.y = red[0].y + red[1].y + red[2].y + red[3].y;
        ssum.z = red[0].z + red[1].z + red[2].z + red[3].z;
        ssum.w = red[0].w + red[1].w + red[2].w + red[3].w;
        *(float4*)(out + (size_t)b * HD)     = smax;
        *(float4*)(out + (size_t)b * HD + 4) = ssum;
    }
}

// ---------------------------------------------------------------------------
// K3: attn = e/(sum+eps) (in place over logits); z = sum attn*x;
//     graph_emb[b,:] = z @ Wt + (sum attn)*bt
// ---------------------------------------------------------------------------
__global__ __launch_bounds__(256) void k3_pool(
    const int* __restrict__ batch, const float* __restrict__ x,
    const float* __restrict__ Wt, const float* __restrict__ bt,
    float* __restrict__ out, int N)
{
    const int b = blockIdx.x;
    const int tid = threadIdx.x;
    const int start = lower_bound(batch, N, b);
    const int end   = lower_bound(batch, N, b + 1);

    float4* at4 = (float4*)(out + (size_t)NSEG * HD);   // logits now, attn after

    const float4 smax = *(const float4*)(out + (size_t)b * HD);
    const float4 ssum = *(const float4*)(out + (size_t)b * HD + 4);
    float4 inv;
    inv.x = 1.0f / (ssum.x + 1e-16f); inv.y = 1.0f / (ssum.y + 1e-16f);
    inv.z = 1.0f / (ssum.z + 1e-16f); inv.w = 1.0f / (ssum.w + 1e-16f);

    float z0 = 0.f, z1 = 0.f, z2 = 0.f, z3 = 0.f;
    __shared__ float4 attn_s[256];

    for (int c0 = start; c0 < end; c0 += 256) {
        const int idx = c0 + tid;
        if (idx < end) {
            float4 l = at4[idx];
            float4 a;
            a.x = __expf(l.x - smax.x) * inv.x;
            a.y = __expf(l.y - smax.y) * inv.y;
            a.z = __expf(l.z - smax.z) * inv.z;
            a.w = __expf(l.w - smax.w) * inv.w;
            at4[idx] = a;          // final attn output
            attn_s[tid] = a;
        }
        __syncthreads();
        const int cnt = min(256, end - c0);
        const float* xb = x + (size_t)c0 * HD + tid;
        #pragma unroll 4
        for (int i = 0; i < cnt; ++i) {
            float4 a = attn_s[i];
            float xv = xb[(size_t)i * HD];
            z0 = fmaf(a.x, xv, z0); z1 = fmaf(a.y, xv, z1);
            z2 = fmaf(a.z, xv, z2); z3 = fmaf(a.w, xv, z3);
        }
        __syncthreads();
    }

    __shared__ float zs[NHEAD][HD];
    zs[0][tid] = z0; zs[1][tid] = z1; zs[2][tid] = z2; zs[3][tid] = z3;
    __syncthreads();

    const int h = tid >> 6;                      // wave-uniform
    float smh, invh;
    if      (h == 0) { smh = ssum.x; invh = inv.x; }
    else if (h == 1) { smh = ssum.y; invh = inv.y; }
    else if (h == 2) { smh = ssum.z; invh = inv.z; }
    else             { smh = ssum.w; invh = inv.w; }

    float acc = smh * invh * bt[tid];            // (sum attn_h) * bt[j]
    #pragma unroll 4
    for (int k = 0; k < HD; ++k)
        acc = fmaf(zs[h][k], Wt[(size_t)k * HD + tid], acc);

    out[(size_t)b * HD + tid] = acc;             // overwrites stats stash: ok
}

// ---------------------------------------------------------------------------
extern "C" void kernel_launch(void* const* d_in, const int* in_sizes, int n_in,
                              void* d_out, int out_size, void* d_ws, size_t ws_size,
                              hipStream_t stream) {
    const float* x   = (const float*)d_in[0];
    const int*   bat = (const int*)  d_in[1];
    const float* W1  = (const float*)d_in[2];
    const float* b1  = (const float*)d_in[3];
    const float* W2  = (const float*)d_in[4];
    const float* b2  = (const float*)d_in[5];
    const float* Wt  = (const float*)d_in[6];
    const float* bt  = (const float*)d_in[7];
    float* out = (float*)d_out;
    const int N = in_sizes[0] / HD;

    float* out_lg = out + (size_t)NSEG * HD;   // attn region of d_out

    hipLaunchKernelGGL(k1_mfma, dim3((N + BM - 1) / BM), dim3(K1_THREADS),
                       K1_LDS, stream, x, W1, b1, W2, b2, out_lg, N);
    hipLaunchKernelGGL(k2_seg, dim3(NSEG), dim3(256), 0, stream, bat, out_lg, out, N);
    hipLaunchKernelGGL(k3_pool, dim3(NSEG), dim3(256), 0, stream, bat, x, Wt, bt, out, N);
}

// Round 5
// 393.254 us; speedup vs baseline: 1.5609x; 1.5609x over previous
//
#include <hip/hip_runtime.h>
#include <math.h>

#define HD    256
#define NHEAD 4
#define NSEG  1024

typedef short bf16x8 __attribute__((ext_vector_type(8)));
typedef float f32x16 __attribute__((ext_vector_type(16)));

__device__ __forceinline__ float tanh_fast(float v) {
    float e = __expf(2.0f * v);                    // overflow->inf, tanh->1: ok
    return 1.0f - 2.0f * __builtin_amdgcn_rcpf(e + 1.0f);
}

// split fp32 pair into packed bf16-hi word and bf16-lo word (truncation split;
// lo captures mantissa bits 9..17 -> per-product rel err ~2^-17)
__device__ __forceinline__ void split2(float a, float b, unsigned &hi, unsigned &lo) {
    unsigned ba = __float_as_uint(a), bb = __float_as_uint(b);
    unsigned ha = ba & 0xFFFF0000u, hb = bb & 0xFFFF0000u;
    float la = a - __uint_as_float(ha);
    float lb = b - __uint_as_float(hb);
    hi = (ha >> 16) | hb;
    lo = (__float_as_uint(la) >> 16) | (__float_as_uint(lb) & 0xFFFF0000u);
}

__device__ __forceinline__ void gld16(const void* g, void* l) {
    __builtin_amdgcn_global_load_lds(
        (const __attribute__((address_space(1))) void*)g,
        (__attribute__((address_space(3))) void*)l, 16, 0, 0);
}

// ---------------------------------------------------------------------------
// k0_prep: W1 (fp32 [k][c]) -> ws as split-bf16 planes, laid out EXACTLY as
// the per-chunk LDS image k1 reads: chunk t (KC=32):
//   byte off = t*32768 + plane*16384 + hoct*4096 + c*16 + j*4
// where hoct = (k_local>>3) in 0..3, j = (k_local&7)>>1 word index (k pair).
// ---------------------------------------------------------------------------
__global__ __launch_bounds__(256) void k0_prep(
    const float* __restrict__ W1, char* __restrict__ ws)
{
    int g = blockIdx.x * 256 + threadIdx.x;        // 32768 threads
    int c  = g & 255;
    int j  = (g >> 8) & 3;
    int h  = (g >> 10) & 3;
    int t  = g >> 12;
    int k  = t*32 + h*8 + 2*j;
    float a = W1[(size_t)k * HD + c];
    float b = W1[(size_t)(k + 1) * HD + c];
    unsigned hw, lw;
    split2(a, b, hw, lw);
    size_t off = (size_t)t*32768 + h*4096 + c*16 + j*4;
    *(unsigned*)(ws + off)         = hw;
    *(unsigned*)(ws + off + 16384) = lw;
}

// ---------------------------------------------------------------------------
// K1: logits = tanh(x @ W1 + b1) @ W2 + b2  via split-bf16 MFMA.
// 512 thr = 8 waves: rg = wid>>1 (4 row groups x 64 rows), cg = wid&1
// (2 col groups x 128 cols): wave = 64 rows x 128 cols = 2 rt x 4 ct of
// 32x32 mfma; x-row duplication across waves = 2 (L1/LDS absorbs).
// Double-buffered chunks of KC=32: per buffer [x fp32 32K | W planes 32K];
// x staged via global_load_lds w/ source-side slot^=(row&7) swizzle; W staged
// via global_load_lds from pre-split ws (k0_prep). One barrier per chunk;
// next-chunk loads issued BEFORE compute so the barrier's vmcnt-drain
// overlaps the 48-MFMA compute phase.
// ---------------------------------------------------------------------------
#define K1_THREADS 512
#define BM 256
#define KC 32
#define NCHUNK (HD/KC)
#define BUFB 65536                                  // bytes per buffer
#define K1_LDS (2*BUFB)

__global__ __launch_bounds__(K1_THREADS, 2) void k1_mfma(
    const float* __restrict__ x, const char* __restrict__ wsW,
    const float* __restrict__ b1, const float* __restrict__ W2,
    const float* __restrict__ b2, float* __restrict__ out_lg, int N)
{
    extern __shared__ __align__(16) char smem[];

    const int tid  = threadIdx.x;
    const int lane = tid & 63;
    const int lo5  = lane & 31;
    const int hi   = lane >> 5;
    const int wid  = tid >> 6;
    const int rg   = wid >> 1;                     // 0..3
    const int cg   = wid & 1;                      // 0..1
    const int C0   = cg * 128;
    const int blkrow = blockIdx.x * BM;

    f32x16 acc[2][4];
    #pragma unroll
    for (int ct = 0; ct < 4; ++ct) {
        float b1v = b1[C0 + ct*32 + lo5];
        #pragma unroll
        for (int rt = 0; rt < 2; ++rt)
            #pragma unroll
            for (int e = 0; e < 16; ++e)
                acc[rt][ct][e] = b1v;
    }

    // stage source pointers (fixed per thread; advance by chunk)
    const char* gx[4];
    #pragma unroll
    for (int i = 0; i < 4; ++i) {
        int p    = i*8192 + tid*16;                // LDS x-region offset
        int row  = p >> 7;                         // 0..255
        int slot = (p >> 4) & 7;
        long grow = blkrow + row; if (grow > N-1) grow = N-1;
        gx[i] = (const char*)x + grow*1024 + ((slot ^ (row & 7)) * 16);
    }
    const char* gw[4];
    #pragma unroll
    for (int j = 0; j < 4; ++j)
        gw[j] = wsW + j*8192 + tid*16;

    // prologue: stage chunk 0 into buffer 0
    #pragma unroll
    for (int i = 0; i < 4; ++i) gld16(gx[i], smem + i*8192 + tid*16);
    #pragma unroll
    for (int j = 0; j < 4; ++j) gld16(gw[j], smem + 32768 + j*8192 + tid*16);
    __syncthreads();

    for (int t = 0; t < NCHUNK; ++t) {
        const int buf  = (t & 1) * BUFB;
        const int nbuf = BUFB - buf;
        if (t < NCHUNK-1) {                        // issue next chunk (async)
            #pragma unroll
            for (int i = 0; i < 4; ++i)
                gld16(gx[i] + (size_t)(t+1)*128, smem + nbuf + i*8192 + tid*16);
            #pragma unroll
            for (int j = 0; j < 4; ++j)
                gld16(gw[j] + (size_t)(t+1)*32768, smem + nbuf + 32768 + j*8192 + tid*16);
        }
        #pragma unroll
        for (int ks = 0; ks < 2; ++ks) {           // 2 k-steps of 16
            union { unsigned u[4]; bf16x8 v; } ah[2], al[2];
            #pragma unroll
            for (int rt = 0; rt < 2; ++rt) {       // A: x fp32 from LDS, split in-reg
                int rl = rg*64 + rt*32 + lo5;      // local row 0..255
                int base = buf + rl*128;
                int s0 = (ks*4 + hi*2)     ^ (rl & 7);
                int s1 = (ks*4 + hi*2 + 1) ^ (rl & 7);
                float4 q0 = *(const float4*)(smem + base + s0*16);
                float4 q1 = *(const float4*)(smem + base + s1*16);
                split2(q0.x, q0.y, ah[rt].u[0], al[rt].u[0]);
                split2(q0.z, q0.w, ah[rt].u[1], al[rt].u[1]);
                split2(q1.x, q1.y, ah[rt].u[2], al[rt].u[2]);
                split2(q1.z, q1.w, ah[rt].u[3], al[rt].u[3]);
            }
            bf16x8 bh[4], bl[4];
            #pragma unroll
            for (int ct = 0; ct < 4; ++ct) {
                int col = C0 + ct*32 + lo5;
                int off = buf + 32768 + (ks*2 + hi)*4096 + col*16;
                bh[ct] = *(const bf16x8*)(smem + off);
                bl[ct] = *(const bf16x8*)(smem + off + 16384);
            }
            #pragma unroll
            for (int rt = 0; rt < 2; ++rt)
                #pragma unroll
                for (int ct = 0; ct < 4; ++ct) {
                    acc[rt][ct] = __builtin_amdgcn_mfma_f32_32x32x16_bf16(ah[rt].v, bh[ct], acc[rt][ct], 0, 0, 0);
                    acc[rt][ct] = __builtin_amdgcn_mfma_f32_32x32x16_bf16(ah[rt].v, bl[ct], acc[rt][ct], 0, 0, 0);
                    acc[rt][ct] = __builtin_amdgcn_mfma_f32_32x32x16_bf16(al[rt].v, bh[ct], acc[rt][ct], 0, 0, 0);
                }
        }
        __syncthreads();                           // drains stage vmcnt + barrier
    }

    // epilogue: tanh -> h@W2 partial per lane -> butterfly over 32-lane half
    #pragma unroll
    for (int rt = 0; rt < 2; ++rt)
        #pragma unroll
        for (int ct = 0; ct < 4; ++ct)
            #pragma unroll
            for (int e = 0; e < 16; ++e)
                acc[rt][ct][e] = tanh_fast(acc[rt][ct][e]);

    float4 w2v[4];
    #pragma unroll
    for (int ct = 0; ct < 4; ++ct)
        w2v[ct] = *(const float4*)(W2 + (size_t)(C0 + ct*32 + lo5) * NHEAD);

    float4 mine = make_float4(0.f, 0.f, 0.f, 0.f);
    #pragma unroll
    for (int rt = 0; rt < 2; ++rt) {
        #pragma unroll
        for (int e = 0; e < 16; ++e) {
            float s0 = 0.f, s1 = 0.f, s2 = 0.f, s3 = 0.f;
            #pragma unroll
            for (int ct = 0; ct < 4; ++ct) {
                float tv = acc[rt][ct][e];
                s0 = fmaf(tv, w2v[ct].x, s0);
                s1 = fmaf(tv, w2v[ct].y, s1);
                s2 = fmaf(tv, w2v[ct].z, s2);
                s3 = fmaf(tv, w2v[ct].w, s3);
            }
            #pragma unroll
            for (int o = 16; o >= 1; o >>= 1) {    // offsets <32: halves stay separate
                s0 += __shfl_xor(s0, o, 64);
                s1 += __shfl_xor(s1, o, 64);
                s2 += __shfl_xor(s2, o, 64);
                s3 += __shfl_xor(s3, o, 64);
            }
            if (lo5 == rt*16 + e) mine = make_float4(s0, s1, s2, s3);
        }
    }
    const int e_m = lo5 & 15, rt_m = lo5 >> 4;
    const int myrow = rg*64 + rt_m*32 + (e_m & 3) + 8*(e_m >> 2) + 4*hi;

    __syncthreads();                               // compute done; reuse smem
    float (*p_lds)[256][4] = (float(*)[256][4])smem;   // [cg][row][4], 8 KiB
    *(float4*)p_lds[cg][myrow] = mine;
    __syncthreads();
    if (tid < BM) {
        int grow = blkrow + tid;
        if (grow < N) {
            float4 a0 = *(float4*)p_lds[0][tid];
            float4 a1 = *(float4*)p_lds[1][tid];
            float4 o;
            o.x = a0.x + a1.x + b2[0];
            o.y = a0.y + a1.y + b2[1];
            o.z = a0.z + a1.z + b2[2];
            o.w = a0.w + a1.w + b2[3];
            *(float4*)(out_lg + (size_t)grow * NHEAD) = o;
        }
    }
}

// ---------------------------------------------------------------------------
__device__ __forceinline__ int lower_bound(const int* __restrict__ a, int n, int v) {
    int lo = 0, hi = n;
    while (lo < hi) { int m = (lo + hi) >> 1; if (a[m] < v) lo = m + 1; else hi = m; }
    return lo;
}

// ---------------------------------------------------------------------------
// K2: per-segment max & sum-of-exp of logits; stats stashed at out[b*256+0..7]
// ---------------------------------------------------------------------------
__global__ __launch_bounds__(256) void k2_seg(
    const int* __restrict__ batch, const float* __restrict__ lg,
    float* __restrict__ out, int N)
{
    const int b = blockIdx.x;
    const int tid = threadIdx.x;
    const int lane = tid & 63, wid = tid >> 6;
    const int start = lower_bound(batch, N, b);
    const int end   = lower_bound(batch, N, b + 1);
    const float4* lg4 = (const float4*)lg;

    float4 mx = make_float4(-INFINITY, -INFINITY, -INFINITY, -INFINITY);
    for (int i = start + tid; i < end; i += 256) {
        float4 l = lg4[i];
        mx.x = fmaxf(mx.x, l.x); mx.y = fmaxf(mx.y, l.y);
        mx.z = fmaxf(mx.z, l.z); mx.w = fmaxf(mx.w, l.w);
    }
    #pragma unroll
    for (int ofs = 32; ofs >= 1; ofs >>= 1) {
        mx.x = fmaxf(mx.x, __shfl_xor(mx.x, ofs, 64));
        mx.y = fmaxf(mx.y, __shfl_xor(mx.y, ofs, 64));
        mx.z = fmaxf(mx.z, __shfl_xor(mx.z, ofs, 64));
        mx.w = fmaxf(mx.w, __shfl_xor(mx.w, ofs, 64));
    }
    __shared__ float4 red[4];
    if (lane == 0) red[wid] = mx;
    __syncthreads();
    float4 smax;
    smax.x = fmaxf(fmaxf(red[0].x, red[1].x), fmaxf(red[2].x, red[3].x));
    smax.y = fmaxf(fmaxf(red[0].y, red[1].y), fmaxf(red[2].y, red[3].y));
    smax.z = fmaxf(fmaxf(red[0].z, red[1].z), fmaxf(red[2].z, red[3].z));
    smax.w = fmaxf(fmaxf(red[0].w, red[1].w), fmaxf(red[2].w, red[3].w));
    __syncthreads();

    float4 sm = make_float4(0.f, 0.f, 0.f, 0.f);
    for (int i = start + tid; i < end; i += 256) {
        float4 l = lg4[i];
        sm.x += __expf(l.x - smax.x); sm.y += __expf(l.y - smax.y);
        sm.z += __expf(l.z - smax.z); sm.w += __expf(l.w - smax.w);
    }
    #pragma unroll
    for (int ofs = 32; ofs >= 1; ofs >>= 1) {
        sm.x += __shfl_xor(sm.x, ofs, 64);
        sm.y += __shfl_xor(sm.y, ofs, 64);
        sm.z += __shfl_xor(sm.z, ofs, 64);
        sm.w += __shfl_xor(sm.w, ofs, 64);
    }
    if (lane == 0) red[wid] = sm;
    __syncthreads();
    if (tid == 0) {
        float4 ssum;
        ssum.x = red[0].x + red[1].x + red[2].x + red[3].x;
        ssum.y = red[0].y + red[1].y + red[2].y + red[3].y;
        ssum.z = red[0].z + red[1].z + red[2].z + red[3].z;
        ssum.w = red[0].w + red[1].w + red[2].w + red[3].w;
        *(float4*)(out + (size_t)b * HD)     = smax;
        *(float4*)(out + (size_t)b * HD + 4) = ssum;
    }
}

// ---------------------------------------------------------------------------
// K3: attn = e/(sum+eps) (in place over logits); z = sum attn*x;
//     graph_emb[b,:] = z @ Wt + (sum attn)*bt
// ---------------------------------------------------------------------------
__global__ __launch_bounds__(256) void k3_pool(
    const int* __restrict__ batch, const float* __restrict__ x,
    const float* __restrict__ Wt, const float* __restrict__ bt,
    float* __restrict__ out, int N)
{
    const int b = blockIdx.x;
    const int tid = threadIdx.x;
    const int start = lower_bound(batch, N, b);
    const int end   = lower_bound(batch, N, b + 1);

    float4* at4 = (float4*)(out + (size_t)NSEG * HD);   // logits now, attn after

    const float4 smax = *(const float4*)(out + (size_t)b * HD);
    const float4 ssum = *(const float4*)(out + (size_t)b * HD + 4);
    float4 inv;
    inv.x = 1.0f / (ssum.x + 1e-16f); inv.y = 1.0f / (ssum.y + 1e-16f);
    inv.z = 1.0f / (ssum.z + 1e-16f); inv.w = 1.0f / (ssum.w + 1e-16f);

    float z0 = 0.f, z1 = 0.f, z2 = 0.f, z3 = 0.f;
    __shared__ float4 attn_s[256];

    for (int c0 = start; c0 < end; c0 += 256) {
        const int idx = c0 + tid;
        if (idx < end) {
            float4 l = at4[idx];
            float4 a;
            a.x = __expf(l.x - smax.x) * inv.x;
            a.y = __expf(l.y - smax.y) * inv.y;
            a.z = __expf(l.z - smax.z) * inv.z;
            a.w = __expf(l.w - smax.w) * inv.w;
            at4[idx] = a;          // final attn output
            attn_s[tid] = a;
        }
        __syncthreads();
        const int cnt = min(256, end - c0);
        const float* xb = x + (size_t)c0 * HD + tid;
        #pragma unroll 4
        for (int i = 0; i < cnt; ++i) {
            float4 a = attn_s[i];
            float xv = xb[(size_t)i * HD];
            z0 = fmaf(a.x, xv, z0); z1 = fmaf(a.y, xv, z1);
            z2 = fmaf(a.z, xv, z2); z3 = fmaf(a.w, xv, z3);
        }
        __syncthreads();
    }

    __shared__ float zs[NHEAD][HD];
    zs[0][tid] = z0; zs[1][tid] = z1; zs[2][tid] = z2; zs[3][tid] = z3;
    __syncthreads();

    const int h = tid >> 6;                      // wave-uniform
    float smh, invh;
    if      (h == 0) { smh = ssum.x; invh = inv.x; }
    else if (h == 1) { smh = ssum.y; invh = inv.y; }
    else if (h == 2) { smh = ssum.z; invh = inv.z; }
    else             { smh = ssum.w; invh = inv.w; }

    float acc = smh * invh * bt[tid];            // (sum attn_h) * bt[j]
    #pragma unroll 4
    for (int k = 0; k < HD; ++k)
        acc = fmaf(zs[h][k], Wt[(size_t)k * HD + tid], acc);

    out[(size_t)b * HD + tid] = acc;             // overwrites stats stash: ok
}

// ---------------------------------------------------------------------------
extern "C" void kernel_launch(void* const* d_in, const int* in_sizes, int n_in,
                              void* d_out, int out_size, void* d_ws, size_t ws_size,
                              hipStream_t stream) {
    const float* x   = (const float*)d_in[0];
    const int*   bat = (const int*)  d_in[1];
    const float* W1  = (const float*)d_in[2];
    const float* b1  = (const float*)d_in[3];
    const float* W2  = (const float*)d_in[4];
    const float* b2  = (const float*)d_in[5];
    const float* Wt  = (const float*)d_in[6];
    const float* bt  = (const float*)d_in[7];
    float* out = (float*)d_out;
    const int N = in_sizes[0] / HD;

    float* out_lg = out + (size_t)NSEG * HD;   // attn region of d_out

    hipLaunchKernelGGL(k0_prep, dim3(128), dim3(256), 0, stream, W1, (char*)d_ws);
    hipLaunchKernelGGL(k1_mfma, dim3((N + BM - 1) / BM), dim3(K1_THREADS),
                       K1_LDS, stream, x, (const char*)d_ws, b1, W2, b2, out_lg, N);
    hipLaunchKernelGGL(k2_seg, dim3(NSEG), dim3(256), 0, stream, bat, out_lg, out, N);
    hipLaunchKernelGGL(k3_pool, dim3(NSEG), dim3(256), 0, stream, bat, x, Wt, bt, out, N);
}